// Round 1
// 58.505 us; speedup vs baseline: 1.0320x; 1.0320x over previous
//
#include <hip/hip_runtime.h>

// NeuralQuantizer: out[i] = nearest center to x[i], centers = linspace(-1,1,256).
// Closed form: idx = clamp(round((x+1)*127.5), 0, 255); q = -1 + idx*(2/255).
// Memory-bound elementwise op (16.8 MB total traffic, floor ~2.7 us @ 6.3 TB/s).
//
// R1: 2x float4 per thread (block-strided, both loads fully coalesced) to halve
// wave/WG count and double per-wave MLP; nontemporal stores to skip L2
// write-allocate on the never-re-read output. Quantization math kept
// bit-identical to the previous passing kernel (tie-breaking at midpoints is
// threshold-sensitive: absmax already sits at exactly one level spacing).

typedef float f32x4 __attribute__((ext_vector_type(4)));

__device__ __forceinline__ float quant1(float v) {
    float t = (v + 1.0f) * 127.5f;          // keep exact op order (ties!)
    float idx = __builtin_rintf(t);          // round-to-nearest-even
    idx = fminf(fmaxf(idx, 0.0f), 255.0f);   // clamp -> v_med3 style
    return fmaf(idx, 2.0f / 255.0f, -1.0f);
}

__device__ __forceinline__ f32x4 quant4(f32x4 v) {
    f32x4 o;
    o.x = quant1(v.x);
    o.y = quant1(v.y);
    o.z = quant1(v.z);
    o.w = quant1(v.w);
    return o;
}

__global__ __launch_bounds__(256) void quantize_f4x2(const f32x4* __restrict__ x,
                                                     f32x4* __restrict__ out,
                                                     int n4) {
    // Each block owns a contiguous chunk of 512 float4s (256 threads x 2).
    // Both loads are lane-contiguous 16 B -> fully coalesced 1 KiB/wave/instr.
    int i0 = blockIdx.x * 512 + threadIdx.x;
    int i1 = i0 + 256;
    if (i1 < n4) {
        f32x4 a = x[i0];
        f32x4 b = x[i1];
        f32x4 qa = quant4(a);
        f32x4 qb = quant4(b);
        __builtin_nontemporal_store(qa, &out[i0]);
        __builtin_nontemporal_store(qb, &out[i1]);
    } else if (i0 < n4) {
        f32x4 a = x[i0];
        f32x4 qa = quant4(a);
        __builtin_nontemporal_store(qa, &out[i0]);
    }
}

extern "C" void kernel_launch(void* const* d_in, const int* in_sizes, int n_in,
                              void* d_out, int out_size, void* d_ws, size_t ws_size,
                              hipStream_t stream) {
    const f32x4* x = (const f32x4*)d_in[0];
    f32x4* out = (f32x4*)d_out;
    int n = in_sizes[0];                 // 2,097,152 elements — divisible by 4
    int n4 = n / 4;                      // 524,288 float4s
    int per_block = 512;                 // 256 threads x 2 float4
    int grid = (n4 + per_block - 1) / per_block;   // 1024 blocks
    quantize_f4x2<<<grid, 256, 0, stream>>>(x, out, n4);
}